// Round 1
// baseline (561.902 us; speedup 1.0000x reference)
//
#include <hip/hip_runtime.h>

typedef __attribute__((ext_vector_type(4))) float  f32x4;
typedef __attribute__((ext_vector_type(8))) short  s16x8;

static __device__ __forceinline__ short f2bf(float f) {
    unsigned int x = __builtin_bit_cast(unsigned int, f);
    x += 0x7fffu + ((x >> 16) & 1u);
    return (short)(x >> 16);
}

// ---------------- prep kernels ----------------
__global__ __launch_bounds__(256) void castk(const float* __restrict__ in,
                                             short* __restrict__ out, int n) {
    int i = blockIdx.x * 256 + threadIdx.x;
    if (i < n) out[i] = f2bf(in[i]);
}

// WT[c][cin] = W[cin][c], 256x256
__global__ __launch_bounds__(256) void tcast256(const float* __restrict__ in,
                                                short* __restrict__ out) {
    out[blockIdx.x * 256 + threadIdx.x] = f2bf(in[threadIdx.x * 256 + blockIdx.x]);
}

// ---------------- generic 128x128-tile GEMM: C = A * B^T (+bias) ----------------
// A: M x K (f32 or bf16, row-major), B: N x K (bf16, row-major)
template<bool AF32, bool OF32, bool OB16>
__global__ __launch_bounds__(256) void gemm_bt(
    const void* __restrict__ Av, const short* __restrict__ Bm,
    const float* __restrict__ bias,
    float* __restrict__ Cf, short* __restrict__ Cb,
    int M, int N, int K)
{
    __shared__ short lsA[128 * 40];
    __shared__ short lsB[128 * 40];
    const int tid = threadIdx.x;
    const int m0 = blockIdx.x * 128;
    const int n0 = blockIdx.y * 128;
    const int lane = tid & 63;
    const int w = tid >> 6;
    const int wmi = w >> 1, wni = w & 1;
    const int lr = lane & 15, ko = lane >> 4;
    const int r0 = tid >> 1, oc0 = (tid * 2) & 3;

    f32x4 acc[4][4] = {};
    for (int k0 = 0; k0 < K; k0 += 32) {
        __syncthreads();
        if constexpr (AF32) {
            const float* Ap = (const float*)Av + (size_t)(m0 + r0) * K + k0 + oc0 * 8;
            f32x4 a0 = *(const f32x4*)(Ap);
            f32x4 a1 = *(const f32x4*)(Ap + 4);
            f32x4 a2 = *(const f32x4*)(Ap + 8);
            f32x4 a3 = *(const f32x4*)(Ap + 12);
            s16x8 w0, w1;
            #pragma unroll
            for (int j = 0; j < 4; ++j) {
                w0[j] = f2bf(a0[j]); w0[4 + j] = f2bf(a1[j]);
                w1[j] = f2bf(a2[j]); w1[4 + j] = f2bf(a3[j]);
            }
            *(s16x8*)&lsA[r0 * 40 + oc0 * 8]     = w0;
            *(s16x8*)&lsA[r0 * 40 + oc0 * 8 + 8] = w1;
        } else {
            const short* Ap = (const short*)Av + (size_t)(m0 + r0) * K + k0 + oc0 * 8;
            *(s16x8*)&lsA[r0 * 40 + oc0 * 8]     = *(const s16x8*)Ap;
            *(s16x8*)&lsA[r0 * 40 + oc0 * 8 + 8] = *(const s16x8*)(Ap + 8);
        }
        const short* Bp = Bm + (size_t)(n0 + r0) * K + k0 + oc0 * 8;
        *(s16x8*)&lsB[r0 * 40 + oc0 * 8]     = *(const s16x8*)Bp;
        *(s16x8*)&lsB[r0 * 40 + oc0 * 8 + 8] = *(const s16x8*)(Bp + 8);
        __syncthreads();
        #pragma unroll
        for (int mt = 0; mt < 4; ++mt) {
            s16x8 a = *(const s16x8*)&lsA[(wmi * 64 + mt * 16 + lr) * 40 + ko * 8];
            #pragma unroll
            for (int nt = 0; nt < 4; ++nt) {
                s16x8 b = *(const s16x8*)&lsB[(wni * 64 + nt * 16 + lr) * 40 + ko * 8];
                acc[mt][nt] = __builtin_amdgcn_mfma_f32_16x16x32_bf16(a, b, acc[mt][nt], 0, 0, 0);
            }
        }
    }
    const int cr = ko * 4, cc = lr;
    #pragma unroll
    for (int mt = 0; mt < 4; ++mt)
    #pragma unroll
    for (int nt = 0; nt < 4; ++nt) {
        const int col = n0 + wni * 64 + nt * 16 + cc;
        const float bv = bias ? bias[col] : 0.f;
        #pragma unroll
        for (int j = 0; j < 4; ++j) {
            const int row = m0 + wmi * 64 + mt * 16 + cr + j;
            float v = acc[mt][nt][j] + bv;
            size_t idx = (size_t)row * N + col;
            if constexpr (OF32) Cf[idx] = v;
            if constexpr (OB16) Cb[idx] = f2bf(v);
        }
    }
}

// ---------------- scores + softmax over latent k ----------------
// block: (t-chunk 0..7, z=b*G+g). S tile 128(k) x 128(t), softmax over k per column.
__global__ __launch_bounds__(256) void scores_softmax(
    const short* __restrict__ embb, const short* __restrict__ x4b,
    float* __restrict__ attnF, short* __restrict__ attnB)
{
    __shared__ short lsA[128 * 40];
    __shared__ short lsB[128 * 40];
    __shared__ float redm[2 * 128];
    __shared__ float reds[2 * 128];
    const int tid = threadIdx.x;
    const int z = blockIdx.y;
    const int g = z & 15;
    const int t0 = blockIdx.x * 128;
    const short* A = embb + (size_t)g * 32768;
    const short* B = x4b + (size_t)z * 262144 + (size_t)t0 * 256;
    const int lane = tid & 63;
    const int w = tid >> 6;
    const int wmi = w >> 1, wni = w & 1;
    const int lr = lane & 15, ko = lane >> 4;
    const int r0 = tid >> 1, oc0 = (tid * 2) & 3;

    f32x4 acc[4][4] = {};
    for (int k0 = 0; k0 < 256; k0 += 32) {
        __syncthreads();
        const short* Ap = A + (size_t)r0 * 256 + k0 + oc0 * 8;
        *(s16x8*)&lsA[r0 * 40 + oc0 * 8]     = *(const s16x8*)Ap;
        *(s16x8*)&lsA[r0 * 40 + oc0 * 8 + 8] = *(const s16x8*)(Ap + 8);
        const short* Bp = B + (size_t)r0 * 256 + k0 + oc0 * 8;
        *(s16x8*)&lsB[r0 * 40 + oc0 * 8]     = *(const s16x8*)Bp;
        *(s16x8*)&lsB[r0 * 40 + oc0 * 8 + 8] = *(const s16x8*)(Bp + 8);
        __syncthreads();
        #pragma unroll
        for (int mt = 0; mt < 4; ++mt) {
            s16x8 a = *(const s16x8*)&lsA[(wmi * 64 + mt * 16 + lr) * 40 + ko * 8];
            #pragma unroll
            for (int nt = 0; nt < 4; ++nt) {
                s16x8 b = *(const s16x8*)&lsB[(wni * 64 + nt * 16 + lr) * 40 + ko * 8];
                acc[mt][nt] = __builtin_amdgcn_mfma_f32_16x16x32_bf16(a, b, acc[mt][nt], 0, 0, 0);
            }
        }
    }
    const float scale = 0.0625f;  // 1/sqrt(256)
    // per-column (t) max over this wave's 64 rows (latent k)
    float cm[4];
    #pragma unroll
    for (int nt = 0; nt < 4; ++nt) {
        float m = -1e30f;
        #pragma unroll
        for (int mt = 0; mt < 4; ++mt)
            #pragma unroll
            for (int j = 0; j < 4; ++j) m = fmaxf(m, acc[mt][nt][j]);
        m = fmaxf(m, __shfl_xor(m, 16));
        m = fmaxf(m, __shfl_xor(m, 32));
        cm[nt] = m * scale;
    }
    if (lane < 16) {
        #pragma unroll
        for (int nt = 0; nt < 4; ++nt)
            redm[wmi * 128 + wni * 64 + nt * 16 + lr] = cm[nt];
    }
    __syncthreads();
    float cmax[4];
    #pragma unroll
    for (int nt = 0; nt < 4; ++nt) {
        int c = wni * 64 + nt * 16 + lr;
        cmax[nt] = fmaxf(redm[c], redm[128 + c]);
    }
    float cs[4];
    #pragma unroll
    for (int nt = 0; nt < 4; ++nt) {
        float s = 0.f;
        #pragma unroll
        for (int mt = 0; mt < 4; ++mt)
            #pragma unroll
            for (int j = 0; j < 4; ++j) {
                float p = __expf(acc[mt][nt][j] * scale - cmax[nt]);
                acc[mt][nt][j] = p;
                s += p;
            }
        s += __shfl_xor(s, 16);
        s += __shfl_xor(s, 32);
        cs[nt] = s;
    }
    if (lane < 16) {
        #pragma unroll
        for (int nt = 0; nt < 4; ++nt)
            reds[wmi * 128 + wni * 64 + nt * 16 + lr] = cs[nt];
    }
    __syncthreads();
    #pragma unroll
    for (int nt = 0; nt < 4; ++nt) {
        int c = wni * 64 + nt * 16 + lr;
        float inv = 1.f / (reds[c] + reds[128 + c]);
        int col = t0 + c;
        #pragma unroll
        for (int mt = 0; mt < 4; ++mt)
            #pragma unroll
            for (int j = 0; j < 4; ++j) {
                int row = wmi * 64 + mt * 16 + ko * 4 + j;
                float a = acc[mt][nt][j] * inv;
                size_t idx = ((size_t)(z * 128 + row)) * 1024 + col;
                attnF[idx] = a;
                attnB[idx] = f2bf(a);
            }
    }
}

// ---------------- y = attn @ x4 (per b,g) ----------------
// blockIdx: (d-chunk 0..1, z). Transposed B staging with 16B-unit XOR swizzle.
__global__ __launch_bounds__(256) void y_gemm(
    const short* __restrict__ attnB, const short* __restrict__ x4b,
    float* __restrict__ yF, short* __restrict__ yB)
{
    __shared__ short lsA[128 * 40];
    __shared__ short lsB[128 * 40];
    const int tid = threadIdx.x;
    const int z = blockIdx.y;
    const int d0 = blockIdx.x * 128;
    const short* A = attnB + (size_t)z * 131072;
    const short* X = x4b + (size_t)z * 262144 + d0;
    const int lane = tid & 63;
    const int w = tid >> 6;
    const int wmi = w >> 1, wni = w & 1;
    const int lr = lane & 15, ko = lane >> 4;
    const int r0 = tid >> 1, oc0 = (tid * 2) & 3;
    const int rb = tid >> 3, ocb = (tid * 2) & 15;
    f32x4 acc[4][4] = {};
    for (int k0 = 0; k0 < 1024; k0 += 32) {
        __syncthreads();
        const short* Ap = A + (size_t)r0 * 1024 + k0 + oc0 * 8;
        *(s16x8*)&lsA[r0 * 40 + oc0 * 8]     = *(const s16x8*)Ap;
        *(s16x8*)&lsA[r0 * 40 + oc0 * 8 + 8] = *(const s16x8*)(Ap + 8);
        s16x8 v0 = *(const s16x8*)(X + (size_t)(k0 + rb) * 256 + ocb * 8);
        s16x8 v1 = *(const s16x8*)(X + (size_t)(k0 + rb) * 256 + ocb * 8 + 8);
        #pragma unroll
        for (int j = 0; j < 8; ++j) {
            int dd = ocb * 8 + j;
            lsB[dd * 40 + ((((rb >> 3) ^ ((dd >> 4) & 3)) << 3) | (rb & 7))] = v0[j];
            int dd2 = dd + 8;
            lsB[dd2 * 40 + ((((rb >> 3) ^ ((dd2 >> 4) & 3)) << 3) | (rb & 7))] = v1[j];
        }
        __syncthreads();
        #pragma unroll
        for (int mt = 0; mt < 4; ++mt) {
            s16x8 a = *(const s16x8*)&lsA[(wmi * 64 + mt * 16 + lr) * 40 + ko * 8];
            #pragma unroll
            for (int nt = 0; nt < 4; ++nt) {
                int dd = wni * 64 + nt * 16 + lr;
                s16x8 b = *(const s16x8*)&lsB[dd * 40 + ((ko ^ ((dd >> 4) & 3)) << 3)];
                acc[mt][nt] = __builtin_amdgcn_mfma_f32_16x16x32_bf16(a, b, acc[mt][nt], 0, 0, 0);
            }
        }
    }
    const int cr = ko * 4, cc = lr;
    #pragma unroll
    for (int mt = 0; mt < 4; ++mt)
    #pragma unroll
    for (int nt = 0; nt < 4; ++nt)
        #pragma unroll
        for (int j = 0; j < 4; ++j) {
            int krow = wmi * 64 + mt * 16 + cr + j;
            int col = d0 + wni * 64 + nt * 16 + cc;
            float v = acc[mt][nt][j];
            size_t idx = ((size_t)(z * 128 + krow)) * 256 + col;
            yF[idx] = v;
            yB[idx] = f2bf(v);
        }
}

// ---------------- per-(nb,h) MHA: s2 = qk^T, softmax rows, o = a v ----------------
__global__ __launch_bounds__(256) void mha(
    const short* __restrict__ qkvb, short* __restrict__ ob)
{
    __shared__ short la[128 * 136];   // attn bf16; also overlays lq/lk below
    __shared__ short lvt[32 * 136];   // v transposed [d][s]
    __shared__ float redm[2 * 128];
    __shared__ float reds[2 * 128];
    short* lq = la;                   // [128][40]
    short* lk = la + 128 * 40;        // [128][40]
    const int tid = threadIdx.x;
    const int nb = blockIdx.x >> 3;
    const int h = blockIdx.x & 7;
    const int lane = tid & 63;
    const int w = tid >> 6;
    const int wmi = w >> 1, wni = w & 1;
    const int lr = lane & 15, ko = lane >> 4;
    const int sv = tid >> 1, oc0 = (tid * 2) & 3;
    {
        const short* qp = qkvb + ((size_t)sv * 128 + nb) * 768 + h * 32 + oc0 * 8;
        *(s16x8*)&lq[sv * 40 + oc0 * 8]     = *(const s16x8*)qp;
        *(s16x8*)&lq[sv * 40 + oc0 * 8 + 8] = *(const s16x8*)(qp + 8);
        const short* kp = qp + 256;
        *(s16x8*)&lk[sv * 40 + oc0 * 8]     = *(const s16x8*)kp;
        *(s16x8*)&lk[sv * 40 + oc0 * 8 + 8] = *(const s16x8*)(kp + 8);
        const short* vp = qp + 512;
        s16x8 v0 = *(const s16x8*)vp;
        s16x8 v1 = *(const s16x8*)(vp + 8);
        #pragma unroll
        for (int j = 0; j < 8; ++j) {
            lvt[(oc0 * 8 + j) * 136 + sv]     = v0[j];
            lvt[(oc0 * 8 + 8 + j) * 136 + sv] = v1[j];
        }
    }
    __syncthreads();
    f32x4 acc[4][4] = {};
    #pragma unroll
    for (int mt = 0; mt < 4; ++mt) {
        s16x8 a = *(const s16x8*)&lq[(wmi * 64 + mt * 16 + lr) * 40 + ko * 8];
        #pragma unroll
        for (int nt = 0; nt < 4; ++nt) {
            s16x8 b = *(const s16x8*)&lk[(wni * 64 + nt * 16 + lr) * 40 + ko * 8];
            acc[mt][nt] = __builtin_amdgcn_mfma_f32_16x16x32_bf16(a, b, acc[mt][nt], 0, 0, 0);
        }
    }
    const float scale = 0.1767766953f;  // 1/sqrt(32)
    // row-softmax (over t2)
    float rm[4][4];
    #pragma unroll
    for (int mt = 0; mt < 4; ++mt)
        #pragma unroll
        for (int j = 0; j < 4; ++j) {
            float m = -1e30f;
            #pragma unroll
            for (int nt = 0; nt < 4; ++nt) m = fmaxf(m, acc[mt][nt][j]);
            m = fmaxf(m, __shfl_xor(m, 1));
            m = fmaxf(m, __shfl_xor(m, 2));
            m = fmaxf(m, __shfl_xor(m, 4));
            m = fmaxf(m, __shfl_xor(m, 8));
            rm[mt][j] = m * scale;
        }
    if (lr == 0) {
        #pragma unroll
        for (int mt = 0; mt < 4; ++mt)
            #pragma unroll
            for (int j = 0; j < 4; ++j)
                redm[wni * 128 + wmi * 64 + mt * 16 + ko * 4 + j] = rm[mt][j];
    }
    __syncthreads();
    float rs[4][4];
    #pragma unroll
    for (int mt = 0; mt < 4; ++mt)
        #pragma unroll
        for (int j = 0; j < 4; ++j) {
            int row = wmi * 64 + mt * 16 + ko * 4 + j;
            float mx = fmaxf(redm[row], redm[128 + row]);
            float s = 0.f;
            #pragma unroll
            for (int nt = 0; nt < 4; ++nt) {
                float p = __expf(acc[mt][nt][j] * scale - mx);
                acc[mt][nt][j] = p;
                s += p;
            }
            s += __shfl_xor(s, 1);
            s += __shfl_xor(s, 2);
            s += __shfl_xor(s, 4);
            s += __shfl_xor(s, 8);
            rs[mt][j] = s;
        }
    if (lr == 0) {
        #pragma unroll
        for (int mt = 0; mt < 4; ++mt)
            #pragma unroll
            for (int j = 0; j < 4; ++j)
                reds[wni * 128 + wmi * 64 + mt * 16 + ko * 4 + j] = rs[mt][j];
    }
    __syncthreads();
    // write attn bf16 into la (overlays lq/lk — all reads done)
    #pragma unroll
    for (int mt = 0; mt < 4; ++mt)
        #pragma unroll
        for (int j = 0; j < 4; ++j) {
            int row = wmi * 64 + mt * 16 + ko * 4 + j;
            float inv = 1.f / (reds[row] + reds[128 + row]);
            #pragma unroll
            for (int nt = 0; nt < 4; ++nt) {
                int col = wni * 64 + nt * 16 + lr;
                la[row * 136 + col] = f2bf(acc[mt][nt][j] * inv);
            }
        }
    __syncthreads();
    // o = a @ v : 128 x 32, wave w owns rows w*32..w*32+31
    f32x4 acc2[2][2] = {};
    #pragma unroll
    for (int ks = 0; ks < 4; ++ks)
        #pragma unroll
        for (int mt = 0; mt < 2; ++mt) {
            s16x8 a = *(const s16x8*)&la[(w * 32 + mt * 16 + lr) * 136 + ks * 32 + ko * 8];
            #pragma unroll
            for (int nt = 0; nt < 2; ++nt) {
                s16x8 b = *(const s16x8*)&lvt[(nt * 16 + lr) * 136 + ks * 32 + ko * 8];
                acc2[mt][nt] = __builtin_amdgcn_mfma_f32_16x16x32_bf16(a, b, acc2[mt][nt], 0, 0, 0);
            }
        }
    const int cr = ko * 4, cc = lr;
    #pragma unroll
    for (int mt = 0; mt < 2; ++mt)
    #pragma unroll
    for (int nt = 0; nt < 2; ++nt)
        #pragma unroll
        for (int j = 0; j < 4; ++j) {
            int s = w * 32 + mt * 16 + cr + j;
            int d = nt * 16 + cc;
            ob[((size_t)s * 128 + nb) * 256 + h * 32 + d] = f2bf(acc2[mt][nt][j]);
        }
}

// ---------------- residual + layernorm (one row of 256 per block) ----------------
__global__ __launch_bounds__(256) void ln_res(
    const float* __restrict__ zin, const float* __restrict__ res,
    const float* __restrict__ gw, const float* __restrict__ gb,
    float* __restrict__ outF, short* __restrict__ outB)
{
    const int row = blockIdx.x;
    const int t = threadIdx.x;
    const size_t idx = (size_t)row * 256 + t;
    float v = zin[idx] + res[idx];
    float s1 = v, s2 = v * v;
    #pragma unroll
    for (int o = 1; o < 64; o <<= 1) {
        s1 += __shfl_xor(s1, o);
        s2 += __shfl_xor(s2, o);
    }
    __shared__ float ps[8];
    const int wv = t >> 6;
    if ((t & 63) == 0) { ps[wv] = s1; ps[4 + wv] = s2; }
    __syncthreads();
    float S1 = ps[0] + ps[1] + ps[2] + ps[3];
    float S2 = ps[4] + ps[5] + ps[6] + ps[7];
    float m = S1 * 0.00390625f;
    float var = S2 * 0.00390625f - m * m;
    float rstd = rsqrtf(var + 1e-5f);
    float o = (v - m) * rstd * gw[t] + gb[t];
    outF[idx] = o;
    outB[idx] = f2bf(o);
}

extern "C" void kernel_launch(void* const* d_in, const int* in_sizes, int n_in,
                              void* d_out, int out_size, void* d_ws, size_t ws_size,
                              hipStream_t stream)
{
    const float* x    = (const float*)d_in[0];
    const float* Wlin = (const float*)d_in[1];
    const float* blin = (const float*)d_in[2];
    const float* emb  = (const float*)d_in[3];
    const float* ipw  = (const float*)d_in[4];
    const float* ipb  = (const float*)d_in[5];
    const float* outw = (const float*)d_in[6];
    const float* outb = (const float*)d_in[7];
    const float* linw = (const float*)d_in[8];
    const float* linb = (const float*)d_in[9];
    const float* ln1w = (const float*)d_in[10];
    const float* ln1b = (const float*)d_in[11];
    const float* ln2w = (const float*)d_in[12];
    const float* ln2b = (const float*)d_in[13];

    char* ws = (char*)d_ws;
    short* x4_b   = (short*)(ws);                       // 67,108,864 B
    short* attn_b = (short*)(ws + 67108864);            // 33,554,432 B
    float* yF     = (float*)(ws + 100663296);           // 16,777,216 B
    short* y_b    = (short*)(ws + 117440512);           //  8,388,608 B
    char*  wb     = ws + 125829120;                     // weights ~2.5 MB (peak ~128.4 MB)
    short* WT_b   = (short*)(wb);
    short* emb_b  = (short*)(wb + 131072);
    short* inw_b  = (short*)(wb + 131072 + 1048576);
    short* outw_b = (short*)(wb + 131072 + 1048576 + 786432);
    short* linw_b = (short*)(wb + 131072 + 1048576 + 786432 + 262144);
    // post-y overlays (x4_b/attn_b dead after y_gemm):
    short* qkv_b  = (short*)(ws);                       // 25,165,824 B
    short* o_b    = (short*)(ws + 25165824);            //  8,388,608 B
    float* op     = (float*)(ws + 33554432);            // 16,777,216 B

    float* out_y    = (float*)d_out;                    // 4,194,304 floats
    float* out_attn = (float*)d_out + 4194304;          // 16,777,216 floats

    castk<<<dim3(2048), dim3(256), 0, stream>>>(emb, emb_b, 524288);
    castk<<<dim3(1536), dim3(256), 0, stream>>>(ipw, inw_b, 393216);
    castk<<<dim3(512),  dim3(256), 0, stream>>>(outw, outw_b, 131072);
    castk<<<dim3(512),  dim3(256), 0, stream>>>(linw, linw_b, 131072);
    tcast256<<<dim3(256), dim3(256), 0, stream>>>(Wlin, WT_b);

    // x4 = x @ Wlin + b  (M=131072, N=256, K=256), bf16 out
    gemm_bt<true, false, true><<<dim3(1024, 2), dim3(256), 0, stream>>>(
        x, WT_b, blin, nullptr, x4_b, 131072, 256, 256);
    // scores + softmax over latent k; attn -> d_out (f32) + ws (bf16)
    scores_softmax<<<dim3(8, 128), dim3(256), 0, stream>>>(emb_b, x4_b, out_attn, attn_b);
    // y = attn @ x4  -> yF (f32) + y_b (bf16)
    y_gemm<<<dim3(2, 128), dim3(256), 0, stream>>>(attn_b, x4_b, yF, y_b);

    for (int i = 0; i < 2; ++i) {
        gemm_bt<false, false, true><<<dim3(128, 6), dim3(256), 0, stream>>>(
            y_b, inw_b + i * 196608, ipb + i * 768, nullptr, qkv_b, 16384, 768, 256);
        mha<<<dim3(1024), dim3(256), 0, stream>>>(qkv_b, o_b);
        gemm_bt<false, true, false><<<dim3(128, 2), dim3(256), 0, stream>>>(
            o_b, outw_b + i * 65536, outb + i * 256, op, nullptr, 16384, 256, 256);
        ln_res<<<dim3(16384), dim3(256), 0, stream>>>(
            op, yF, ln1w + i * 256, ln1b + i * 256, yF, y_b);
        gemm_bt<false, true, false><<<dim3(128, 2), dim3(256), 0, stream>>>(
            y_b, linw_b + i * 65536, linb + i * 256, op, nullptr, 16384, 256, 256);
        ln_res<<<dim3(16384), dim3(256), 0, stream>>>(
            op, yF, ln2w + i * 256, ln2b + i * 256, (i == 1) ? out_y : yF, y_b);
    }
}

// Round 2
// 540.877 us; speedup vs baseline: 1.0389x; 1.0389x over previous
//
#include <hip/hip_runtime.h>

typedef __attribute__((ext_vector_type(4))) float  f32x4;
typedef __attribute__((ext_vector_type(8))) short  s16x8;
typedef __attribute__((ext_vector_type(4))) short  s16x4;

static __device__ __forceinline__ short f2bf(float f) {
    unsigned int x = __builtin_bit_cast(unsigned int, f);
    x += 0x7fffu + ((x >> 16) & 1u);
    return (short)(x >> 16);
}

// ---------------- prep kernels ----------------
// fused weight cast: emb 524288, ipw 393216, outw 131072, linw 131072 (f32 -> bf16)
__global__ __launch_bounds__(256) void castall(
    const float* __restrict__ emb, const float* __restrict__ ipw,
    const float* __restrict__ outw, const float* __restrict__ linw,
    short* __restrict__ de, short* __restrict__ di,
    short* __restrict__ dg, short* __restrict__ dl)
{
    int q = blockIdx.x * 256 + threadIdx.x;   // quad index, total 294912
    const float* s; short* d; int o;
    if (q < 131072)      { s = emb;  d = de; o = q; }
    else if (q < 229376) { s = ipw;  d = di; o = q - 131072; }
    else if (q < 262144) { s = outw; d = dg; o = q - 229376; }
    else                 { s = linw; d = dl; o = q - 262144; }
    f32x4 v = *(const f32x4*)(s + (size_t)o * 4);
    s16x4 r;
    #pragma unroll
    for (int j = 0; j < 4; ++j) r[j] = f2bf(v[j]);
    *(s16x4*)(d + (size_t)o * 4) = r;
}

// WT[c][cin] = W[cin][c], 256x256
__global__ __launch_bounds__(256) void tcast256(const float* __restrict__ in,
                                                short* __restrict__ out) {
    out[blockIdx.x * 256 + threadIdx.x] = f2bf(in[threadIdx.x * 256 + blockIdx.x]);
}

// ---------------- generic 128x128-tile GEMM: C = A * B^T (+bias) ----------------
// A: M x K (f32 or bf16, row-major), B: N x K (bf16, row-major)
// T14 prefetch: loads for tile t+1 issued before MFMA of tile t.
template<bool AF32, bool OF32, bool OB16>
__global__ __launch_bounds__(256) void gemm_bt(
    const void* __restrict__ Av, const short* __restrict__ Bm,
    const float* __restrict__ bias,
    float* __restrict__ Cf, short* __restrict__ Cb,
    int M, int N, int K)
{
    __shared__ short lsA[128 * 40];
    __shared__ short lsB[128 * 40];
    const int tid = threadIdx.x;
    const int m0 = blockIdx.x * 128;
    const int n0 = blockIdx.y * 128;
    const int lane = tid & 63;
    const int w = tid >> 6;
    const int wmi = w >> 1, wni = w & 1;
    const int lr = lane & 15, ko = lane >> 4;
    const int r0 = tid >> 1, oc0 = (tid * 2) & 3;

    const float* Apf = (const float*)Av + (size_t)(m0 + r0) * K + oc0 * 8;
    const short* Aps = (const short*)Av + (size_t)(m0 + r0) * K + oc0 * 8;
    const short* Bp  = Bm + (size_t)(n0 + r0) * K + oc0 * 8;

    f32x4 pa0, pa1, pa2, pa3;
    s16x8 pas0, pas1, pb0, pb1;
    if constexpr (AF32) {
        pa0 = *(const f32x4*)(Apf);
        pa1 = *(const f32x4*)(Apf + 4);
        pa2 = *(const f32x4*)(Apf + 8);
        pa3 = *(const f32x4*)(Apf + 12);
    } else {
        pas0 = *(const s16x8*)(Aps);
        pas1 = *(const s16x8*)(Aps + 8);
    }
    pb0 = *(const s16x8*)(Bp);
    pb1 = *(const s16x8*)(Bp + 8);

    f32x4 acc[4][4] = {};
    for (int k0 = 0; k0 < K; k0 += 32) {
        if constexpr (AF32) {
            s16x8 w0, w1;
            #pragma unroll
            for (int j = 0; j < 4; ++j) {
                w0[j] = f2bf(pa0[j]); w0[4 + j] = f2bf(pa1[j]);
                w1[j] = f2bf(pa2[j]); w1[4 + j] = f2bf(pa3[j]);
            }
            *(s16x8*)&lsA[r0 * 40 + oc0 * 8]     = w0;
            *(s16x8*)&lsA[r0 * 40 + oc0 * 8 + 8] = w1;
        } else {
            *(s16x8*)&lsA[r0 * 40 + oc0 * 8]     = pas0;
            *(s16x8*)&lsA[r0 * 40 + oc0 * 8 + 8] = pas1;
        }
        *(s16x8*)&lsB[r0 * 40 + oc0 * 8]     = pb0;
        *(s16x8*)&lsB[r0 * 40 + oc0 * 8 + 8] = pb1;
        __syncthreads();
        if (k0 + 32 < K) {
            const int kn = k0 + 32;
            if constexpr (AF32) {
                pa0 = *(const f32x4*)(Apf + kn);
                pa1 = *(const f32x4*)(Apf + kn + 4);
                pa2 = *(const f32x4*)(Apf + kn + 8);
                pa3 = *(const f32x4*)(Apf + kn + 12);
            } else {
                pas0 = *(const s16x8*)(Aps + kn);
                pas1 = *(const s16x8*)(Aps + kn + 8);
            }
            pb0 = *(const s16x8*)(Bp + kn);
            pb1 = *(const s16x8*)(Bp + kn + 8);
        }
        #pragma unroll
        for (int mt = 0; mt < 4; ++mt) {
            s16x8 a = *(const s16x8*)&lsA[(wmi * 64 + mt * 16 + lr) * 40 + ko * 8];
            #pragma unroll
            for (int nt = 0; nt < 4; ++nt) {
                s16x8 b = *(const s16x8*)&lsB[(wni * 64 + nt * 16 + lr) * 40 + ko * 8];
                acc[mt][nt] = __builtin_amdgcn_mfma_f32_16x16x32_bf16(a, b, acc[mt][nt], 0, 0, 0);
            }
        }
        __syncthreads();
    }
    const int cr = ko * 4, cc = lr;
    #pragma unroll
    for (int mt = 0; mt < 4; ++mt)
    #pragma unroll
    for (int nt = 0; nt < 4; ++nt) {
        const int col = n0 + wni * 64 + nt * 16 + cc;
        const float bv = bias ? bias[col] : 0.f;
        #pragma unroll
        for (int j = 0; j < 4; ++j) {
            const int row = m0 + wmi * 64 + mt * 16 + cr + j;
            float v = acc[mt][nt][j] + bv;
            size_t idx = (size_t)row * N + col;
            if constexpr (OF32) Cf[idx] = v;
            if constexpr (OB16) Cb[idx] = f2bf(v);
        }
    }
}

// ---------------- scores + softmax over latent k ----------------
// block: (t-chunk 0..7, z=b*G+g). S tile 128(k) x 128(t), softmax over k per column.
__global__ __launch_bounds__(256) void scores_softmax(
    const short* __restrict__ embb, const short* __restrict__ x4b,
    float* __restrict__ attnF, short* __restrict__ attnB)
{
    __shared__ short lsA[128 * 40];
    __shared__ short lsB[128 * 40];
    __shared__ float redm[2 * 128];
    __shared__ float reds[2 * 128];
    const int tid = threadIdx.x;
    const int z = blockIdx.y;
    const int g = z & 15;
    const int t0 = blockIdx.x * 128;
    const short* A = embb + (size_t)g * 32768;
    const short* B = x4b + (size_t)z * 262144 + (size_t)t0 * 256;
    const int lane = tid & 63;
    const int w = tid >> 6;
    const int wmi = w >> 1, wni = w & 1;
    const int lr = lane & 15, ko = lane >> 4;
    const int r0 = tid >> 1, oc0 = (tid * 2) & 3;

    const short* Ap = A + (size_t)r0 * 256 + oc0 * 8;
    const short* Bp = B + (size_t)r0 * 256 + oc0 * 8;
    s16x8 pa0 = *(const s16x8*)(Ap);
    s16x8 pa1 = *(const s16x8*)(Ap + 8);
    s16x8 pb0 = *(const s16x8*)(Bp);
    s16x8 pb1 = *(const s16x8*)(Bp + 8);

    f32x4 acc[4][4] = {};
    for (int k0 = 0; k0 < 256; k0 += 32) {
        *(s16x8*)&lsA[r0 * 40 + oc0 * 8]     = pa0;
        *(s16x8*)&lsA[r0 * 40 + oc0 * 8 + 8] = pa1;
        *(s16x8*)&lsB[r0 * 40 + oc0 * 8]     = pb0;
        *(s16x8*)&lsB[r0 * 40 + oc0 * 8 + 8] = pb1;
        __syncthreads();
        if (k0 + 32 < 256) {
            const int kn = k0 + 32;
            pa0 = *(const s16x8*)(Ap + kn);
            pa1 = *(const s16x8*)(Ap + kn + 8);
            pb0 = *(const s16x8*)(Bp + kn);
            pb1 = *(const s16x8*)(Bp + kn + 8);
        }
        #pragma unroll
        for (int mt = 0; mt < 4; ++mt) {
            s16x8 a = *(const s16x8*)&lsA[(wmi * 64 + mt * 16 + lr) * 40 + ko * 8];
            #pragma unroll
            for (int nt = 0; nt < 4; ++nt) {
                s16x8 b = *(const s16x8*)&lsB[(wni * 64 + nt * 16 + lr) * 40 + ko * 8];
                acc[mt][nt] = __builtin_amdgcn_mfma_f32_16x16x32_bf16(a, b, acc[mt][nt], 0, 0, 0);
            }
        }
        __syncthreads();
    }
    const float scale = 0.0625f;  // 1/sqrt(256)
    float cm[4];
    #pragma unroll
    for (int nt = 0; nt < 4; ++nt) {
        float m = -1e30f;
        #pragma unroll
        for (int mt = 0; mt < 4; ++mt)
            #pragma unroll
            for (int j = 0; j < 4; ++j) m = fmaxf(m, acc[mt][nt][j]);
        m = fmaxf(m, __shfl_xor(m, 16));
        m = fmaxf(m, __shfl_xor(m, 32));
        cm[nt] = m * scale;
    }
    if (lane < 16) {
        #pragma unroll
        for (int nt = 0; nt < 4; ++nt)
            redm[wmi * 128 + wni * 64 + nt * 16 + lr] = cm[nt];
    }
    __syncthreads();
    float cmax[4];
    #pragma unroll
    for (int nt = 0; nt < 4; ++nt) {
        int c = wni * 64 + nt * 16 + lr;
        cmax[nt] = fmaxf(redm[c], redm[128 + c]);
    }
    float cs[4];
    #pragma unroll
    for (int nt = 0; nt < 4; ++nt) {
        float s = 0.f;
        #pragma unroll
        for (int mt = 0; mt < 4; ++mt)
            #pragma unroll
            for (int j = 0; j < 4; ++j) {
                float p = __expf(acc[mt][nt][j] * scale - cmax[nt]);
                acc[mt][nt][j] = p;
                s += p;
            }
        s += __shfl_xor(s, 16);
        s += __shfl_xor(s, 32);
        cs[nt] = s;
    }
    if (lane < 16) {
        #pragma unroll
        for (int nt = 0; nt < 4; ++nt)
            reds[wmi * 128 + wni * 64 + nt * 16 + lr] = cs[nt];
    }
    __syncthreads();
    #pragma unroll
    for (int nt = 0; nt < 4; ++nt) {
        int c = wni * 64 + nt * 16 + lr;
        float inv = 1.f / (reds[c] + reds[128 + c]);
        int col = t0 + c;
        #pragma unroll
        for (int mt = 0; mt < 4; ++mt)
            #pragma unroll
            for (int j = 0; j < 4; ++j) {
                int row = wmi * 64 + mt * 16 + ko * 4 + j;
                float a = acc[mt][nt][j] * inv;
                size_t idx = ((size_t)(z * 128 + row)) * 1024 + col;
                attnF[idx] = a;
                attnB[idx] = f2bf(a);
            }
    }
}

// ---------------- y = attn @ x4 (per b,g) ----------------
// blockIdx: (d-chunk 0..1, z). Transposed B staging with 16B-unit XOR swizzle.
__global__ __launch_bounds__(256) void y_gemm(
    const short* __restrict__ attnB, const short* __restrict__ x4b,
    float* __restrict__ yF, short* __restrict__ yB)
{
    __shared__ short lsA[128 * 40];
    __shared__ short lsB[128 * 40];
    const int tid = threadIdx.x;
    const int z = blockIdx.y;
    const int d0 = blockIdx.x * 128;
    const short* A = attnB + (size_t)z * 131072;
    const short* X = x4b + (size_t)z * 262144 + d0;
    const int lane = tid & 63;
    const int w = tid >> 6;
    const int wmi = w >> 1, wni = w & 1;
    const int lr = lane & 15, ko = lane >> 4;
    const int r0 = tid >> 1, oc0 = (tid * 2) & 3;
    const int rb = tid >> 3, ocb = (tid * 2) & 15;

    const short* Ap = A + (size_t)r0 * 1024 + oc0 * 8;
    const short* Xp = X + (size_t)rb * 256 + ocb * 8;

    s16x8 pa0 = *(const s16x8*)(Ap);
    s16x8 pa1 = *(const s16x8*)(Ap + 8);
    s16x8 pv0 = *(const s16x8*)(Xp);
    s16x8 pv1 = *(const s16x8*)(Xp + 8);

    f32x4 acc[4][4] = {};
    for (int k0 = 0; k0 < 1024; k0 += 32) {
        *(s16x8*)&lsA[r0 * 40 + oc0 * 8]     = pa0;
        *(s16x8*)&lsA[r0 * 40 + oc0 * 8 + 8] = pa1;
        #pragma unroll
        for (int j = 0; j < 8; ++j) {
            int dd = ocb * 8 + j;
            lsB[dd * 40 + ((((rb >> 3) ^ ((dd >> 4) & 3)) << 3) | (rb & 7))] = pv0[j];
            int dd2 = dd + 8;
            lsB[dd2 * 40 + ((((rb >> 3) ^ ((dd2 >> 4) & 3)) << 3) | (rb & 7))] = pv1[j];
        }
        __syncthreads();
        if (k0 + 32 < 1024) {
            pa0 = *(const s16x8*)(Ap + k0 + 32);
            pa1 = *(const s16x8*)(Ap + k0 + 40);
            pv0 = *(const s16x8*)(Xp + (size_t)(k0 + 32) * 256);
            pv1 = *(const s16x8*)(Xp + (size_t)(k0 + 32) * 256 + 8);
        }
        #pragma unroll
        for (int mt = 0; mt < 4; ++mt) {
            s16x8 a = *(const s16x8*)&lsA[(wmi * 64 + mt * 16 + lr) * 40 + ko * 8];
            #pragma unroll
            for (int nt = 0; nt < 4; ++nt) {
                int dd = wni * 64 + nt * 16 + lr;
                s16x8 b = *(const s16x8*)&lsB[dd * 40 + ((ko ^ ((dd >> 4) & 3)) << 3)];
                acc[mt][nt] = __builtin_amdgcn_mfma_f32_16x16x32_bf16(a, b, acc[mt][nt], 0, 0, 0);
            }
        }
        __syncthreads();
    }
    const int cr = ko * 4, cc = lr;
    #pragma unroll
    for (int mt = 0; mt < 4; ++mt)
    #pragma unroll
    for (int nt = 0; nt < 4; ++nt)
        #pragma unroll
        for (int j = 0; j < 4; ++j) {
            int krow = wmi * 64 + mt * 16 + cr + j;
            int col = d0 + wni * 64 + nt * 16 + cc;
            float v = acc[mt][nt][j];
            size_t idx = ((size_t)(z * 128 + krow)) * 256 + col;
            yF[idx] = v;
            yB[idx] = f2bf(v);
        }
}

// ---------------- per-(nb,h) MHA: s2 = qk^T, softmax rows, o = a v ----------------
__global__ __launch_bounds__(256) void mha(
    const short* __restrict__ qkvb, short* __restrict__ ob)
{
    __shared__ short la[128 * 136];   // attn bf16; also overlays lq/lk below
    __shared__ short lvt[32 * 136];   // v transposed [d][s]
    __shared__ float redm[2 * 128];
    __shared__ float reds[2 * 128];
    short* lq = la;                   // [128][40]
    short* lk = la + 128 * 40;        // [128][40]
    const int tid = threadIdx.x;
    const int nb = blockIdx.x >> 3;
    const int h = blockIdx.x & 7;
    const int lane = tid & 63;
    const int w = tid >> 6;
    const int wmi = w >> 1, wni = w & 1;
    const int lr = lane & 15, ko = lane >> 4;
    const int sv = tid >> 1, oc0 = (tid * 2) & 3;
    {
        const short* qp = qkvb + ((size_t)sv * 128 + nb) * 768 + h * 32 + oc0 * 8;
        *(s16x8*)&lq[sv * 40 + oc0 * 8]     = *(const s16x8*)qp;
        *(s16x8*)&lq[sv * 40 + oc0 * 8 + 8] = *(const s16x8*)(qp + 8);
        const short* kp = qp + 256;
        *(s16x8*)&lk[sv * 40 + oc0 * 8]     = *(const s16x8*)kp;
        *(s16x8*)&lk[sv * 40 + oc0 * 8 + 8] = *(const s16x8*)(kp + 8);
        const short* vp = qp + 512;
        s16x8 v0 = *(const s16x8*)vp;
        s16x8 v1 = *(const s16x8*)(vp + 8);
        #pragma unroll
        for (int j = 0; j < 8; ++j) {
            lvt[(oc0 * 8 + j) * 136 + sv]     = v0[j];
            lvt[(oc0 * 8 + 8 + j) * 136 + sv] = v1[j];
        }
    }
    __syncthreads();
    f32x4 acc[4][4] = {};
    #pragma unroll
    for (int mt = 0; mt < 4; ++mt) {
        s16x8 a = *(const s16x8*)&lq[(wmi * 64 + mt * 16 + lr) * 40 + ko * 8];
        #pragma unroll
        for (int nt = 0; nt < 4; ++nt) {
            s16x8 b = *(const s16x8*)&lk[(wni * 64 + nt * 16 + lr) * 40 + ko * 8];
            acc[mt][nt] = __builtin_amdgcn_mfma_f32_16x16x32_bf16(a, b, acc[mt][nt], 0, 0, 0);
        }
    }
    const float scale = 0.1767766953f;  // 1/sqrt(32)
    float rm[4][4];
    #pragma unroll
    for (int mt = 0; mt < 4; ++mt)
        #pragma unroll
        for (int j = 0; j < 4; ++j) {
            float m = -1e30f;
            #pragma unroll
            for (int nt = 0; nt < 4; ++nt) m = fmaxf(m, acc[mt][nt][j]);
            m = fmaxf(m, __shfl_xor(m, 1));
            m = fmaxf(m, __shfl_xor(m, 2));
            m = fmaxf(m, __shfl_xor(m, 4));
            m = fmaxf(m, __shfl_xor(m, 8));
            rm[mt][j] = m * scale;
        }
    if (lr == 0) {
        #pragma unroll
        for (int mt = 0; mt < 4; ++mt)
            #pragma unroll
            for (int j = 0; j < 4; ++j)
                redm[wni * 128 + wmi * 64 + mt * 16 + ko * 4 + j] = rm[mt][j];
    }
    __syncthreads();
    float rs[4][4];
    #pragma unroll
    for (int mt = 0; mt < 4; ++mt)
        #pragma unroll
        for (int j = 0; j < 4; ++j) {
            int row = wmi * 64 + mt * 16 + ko * 4 + j;
            float mx = fmaxf(redm[row], redm[128 + row]);
            float s = 0.f;
            #pragma unroll
            for (int nt = 0; nt < 4; ++nt) {
                float p = __expf(acc[mt][nt][j] * scale - mx);
                acc[mt][nt][j] = p;
                s += p;
            }
            s += __shfl_xor(s, 1);
            s += __shfl_xor(s, 2);
            s += __shfl_xor(s, 4);
            s += __shfl_xor(s, 8);
            rs[mt][j] = s;
        }
    if (lr == 0) {
        #pragma unroll
        for (int mt = 0; mt < 4; ++mt)
            #pragma unroll
            for (int j = 0; j < 4; ++j)
                reds[wni * 128 + wmi * 64 + mt * 16 + ko * 4 + j] = rs[mt][j];
    }
    __syncthreads();
    #pragma unroll
    for (int mt = 0; mt < 4; ++mt)
        #pragma unroll
        for (int j = 0; j < 4; ++j) {
            int row = wmi * 64 + mt * 16 + ko * 4 + j;
            float inv = 1.f / (reds[row] + reds[128 + row]);
            #pragma unroll
            for (int nt = 0; nt < 4; ++nt) {
                int col = wni * 64 + nt * 16 + lr;
                la[row * 136 + col] = f2bf(acc[mt][nt][j] * inv);
            }
        }
    __syncthreads();
    f32x4 acc2[2][2] = {};
    #pragma unroll
    for (int ks = 0; ks < 4; ++ks)
        #pragma unroll
        for (int mt = 0; mt < 2; ++mt) {
            s16x8 a = *(const s16x8*)&la[(w * 32 + mt * 16 + lr) * 136 + ks * 32 + ko * 8];
            #pragma unroll
            for (int nt = 0; nt < 2; ++nt) {
                s16x8 b = *(const s16x8*)&lvt[(nt * 16 + lr) * 136 + ks * 32 + ko * 8];
                acc2[mt][nt] = __builtin_amdgcn_mfma_f32_16x16x32_bf16(a, b, acc2[mt][nt], 0, 0, 0);
            }
        }
    const int cr = ko * 4, cc = lr;
    #pragma unroll
    for (int mt = 0; mt < 2; ++mt)
    #pragma unroll
    for (int nt = 0; nt < 2; ++nt)
        #pragma unroll
        for (int j = 0; j < 4; ++j) {
            int s = w * 32 + mt * 16 + cr + j;
            int d = nt * 16 + cc;
            ob[((size_t)s * 128 + nb) * 256 + h * 32 + d] = f2bf(acc2[mt][nt][j]);
        }
}

// ---------------- residual + layernorm (one row of 256 per block) ----------------
__global__ __launch_bounds__(256) void ln_res(
    const float* __restrict__ zin, const float* __restrict__ res,
    const float* __restrict__ gw, const float* __restrict__ gb,
    float* __restrict__ outF, short* __restrict__ outB)
{
    const int row = blockIdx.x;
    const int t = threadIdx.x;
    const size_t idx = (size_t)row * 256 + t;
    float v = zin[idx] + res[idx];
    float s1 = v, s2 = v * v;
    #pragma unroll
    for (int o = 1; o < 64; o <<= 1) {
        s1 += __shfl_xor(s1, o);
        s2 += __shfl_xor(s2, o);
    }
    __shared__ float ps[8];
    const int wv = t >> 6;
    if ((t & 63) == 0) { ps[wv] = s1; ps[4 + wv] = s2; }
    __syncthreads();
    float S1 = ps[0] + ps[1] + ps[2] + ps[3];
    float S2 = ps[4] + ps[5] + ps[6] + ps[7];
    float m = S1 * 0.00390625f;
    float var = S2 * 0.00390625f - m * m;
    float rstd = rsqrtf(var + 1e-5f);
    float o = (v - m) * rstd * gw[t] + gb[t];
    outF[idx] = o;
    outB[idx] = f2bf(o);
}

extern "C" void kernel_launch(void* const* d_in, const int* in_sizes, int n_in,
                              void* d_out, int out_size, void* d_ws, size_t ws_size,
                              hipStream_t stream)
{
    const float* x    = (const float*)d_in[0];
    const float* Wlin = (const float*)d_in[1];
    const float* blin = (const float*)d_in[2];
    const float* emb  = (const float*)d_in[3];
    const float* ipw  = (const float*)d_in[4];
    const float* ipb  = (const float*)d_in[5];
    const float* outw = (const float*)d_in[6];
    const float* outb = (const float*)d_in[7];
    const float* linw = (const float*)d_in[8];
    const float* linb = (const float*)d_in[9];
    const float* ln1w = (const float*)d_in[10];
    const float* ln1b = (const float*)d_in[11];
    const float* ln2w = (const float*)d_in[12];
    const float* ln2b = (const float*)d_in[13];

    char* ws = (char*)d_ws;
    short* x4_b   = (short*)(ws);                       // 67,108,864 B
    short* attn_b = (short*)(ws + 67108864);            // 33,554,432 B
    float* yF     = (float*)(ws + 100663296);           // 16,777,216 B
    short* y_b    = (short*)(ws + 117440512);           //  8,388,608 B
    char*  wb     = ws + 125829120;                     // weights ~2.5 MB (peak ~128.4 MB)
    short* WT_b   = (short*)(wb);
    short* emb_b  = (short*)(wb + 131072);
    short* inw_b  = (short*)(wb + 131072 + 1048576);
    short* outw_b = (short*)(wb + 131072 + 1048576 + 786432);
    short* linw_b = (short*)(wb + 131072 + 1048576 + 786432 + 262144);
    // post-y overlays (x4_b/attn_b dead after y_gemm):
    short* qkv_b  = (short*)(ws);                       // 25,165,824 B
    short* o_b    = (short*)(ws + 25165824);            //  8,388,608 B
    float* op     = (float*)(ws + 33554432);            // 16,777,216 B

    float* out_y    = (float*)d_out;                    // 4,194,304 floats
    float* out_attn = (float*)d_out + 4194304;          // 16,777,216 floats

    castall<<<dim3(1152), dim3(256), 0, stream>>>(emb, ipw, outw, linw,
                                                  emb_b, inw_b, outw_b, linw_b);
    tcast256<<<dim3(256), dim3(256), 0, stream>>>(Wlin, WT_b);

    // x4 = x @ Wlin + b  (M=131072, N=256, K=256), bf16 out
    gemm_bt<true, false, true><<<dim3(1024, 2), dim3(256), 0, stream>>>(
        x, WT_b, blin, nullptr, x4_b, 131072, 256, 256);
    // scores + softmax over latent k; attn -> d_out (f32) + ws (bf16)
    scores_softmax<<<dim3(8, 128), dim3(256), 0, stream>>>(emb_b, x4_b, out_attn, attn_b);
    // y = attn @ x4  -> yF (f32) + y_b (bf16)
    y_gemm<<<dim3(2, 128), dim3(256), 0, stream>>>(attn_b, x4_b, yF, y_b);

    for (int i = 0; i < 2; ++i) {
        gemm_bt<false, false, true><<<dim3(128, 6), dim3(256), 0, stream>>>(
            y_b, inw_b + i * 196608, ipb + i * 768, nullptr, qkv_b, 16384, 768, 256);
        mha<<<dim3(1024), dim3(256), 0, stream>>>(qkv_b, o_b);
        gemm_bt<false, true, false><<<dim3(128, 2), dim3(256), 0, stream>>>(
            o_b, outw_b + i * 65536, outb + i * 256, op, nullptr, 16384, 256, 256);
        ln_res<<<dim3(16384), dim3(256), 0, stream>>>(
            op, yF, ln1w + i * 256, ln1b + i * 256, yF, y_b);
        gemm_bt<false, true, false><<<dim3(128, 2), dim3(256), 0, stream>>>(
            y_b, linw_b + i * 65536, linb + i * 256, op, nullptr, 16384, 256, 256);
        ln_res<<<dim3(16384), dim3(256), 0, stream>>>(
            op, yF, ln2w + i * 256, ln2b + i * 256, (i == 1) ? out_y : yF, y_b);
    }
}